// Round 4
// baseline (4097.150 us; speedup 1.0000x reference)
//
#include <hip/hip_runtime.h>
#include <math.h>

typedef unsigned int u32;
typedef unsigned long long u64;
typedef int iv4 __attribute__((ext_vector_type(4)));
typedef float fv4 __attribute__((ext_vector_type(4)));

#define BKT_BITS 12
#define BKT_SIZE 4096
#define NBMAX    256
#define DEPTH    31          // odd stride: ingest bank=(31b+slot)%32 spreads; 32KB LDS -> 5 blk/CU
#define BIN_T    256
#define TILE     4096        // 4 rounds x 256 thr x int4; mean fill 16.7, P(>31)~3.5sigma
#define SPLIT    4           // sub-blocks per bucket in hist/agg
#define HA_T     512
#define OVFCAP   131072u     // overflow edge capacity (u32 pairs, 1 MB)

// ---------------- fast path ----------------

__global__ void zero_u32(u32* __restrict__ p, int n) {
    int i = blockIdx.x * blockDim.x + threadIdx.x;
    if (i < n) p[i] = 0u;
}

// r0-proven skeleton: oversubscribed grid, LDS staging, ONE flush at block end.
// Fix 1: DEPTH=31 odd stride (kills slot%32 same-bank pattern, 14.1M conflict cyc).
// Fix 2: wave-transposed flush (wave-uniform bucket, contiguous lane stores).
__global__ void __launch_bounds__(BIN_T)
bin_kernel4(const int* __restrict__ src, const int* __restrict__ dst,
            u32* __restrict__ recs, u32* __restrict__ gcursor,
            u32* __restrict__ ovfcnt, u32* __restrict__ ovf,
            int E, int NB, u32 CAP) {
    __shared__ __align__(16) u32 stag[NBMAX * DEPTH];   // 31 KB
    __shared__ u32 scnt[NBMAX];                         // 1 KB -> 32 KB total
    int tid = threadIdx.x;
    for (int t = tid; t < NBMAX; t += BIN_T) scnt[t] = 0u;
    __syncthreads();
    int base = blockIdx.x * TILE;
#pragma unroll
    for (int r = 0; r < TILE / (BIN_T * 4); ++r) {
        int v  = (base >> 2) + r * BIN_T + tid;   // int4 index
        int e0 = v << 2;
        if (e0 + 3 < E) {
            iv4 s4 = __builtin_nontemporal_load(reinterpret_cast<const iv4*>(src) + v);
            iv4 d4 = __builtin_nontemporal_load(reinterpret_cast<const iv4*>(dst) + v);
#pragma unroll
            for (int k = 0; k < 4; ++k) {
                u32 ss = (u32)s4[k], dd = (u32)d4[k];
                u32 b   = dd >> BKT_BITS;
                u32 rec = (ss << BKT_BITS) | (dd & (BKT_SIZE - 1));
                u32 slot = atomicAdd(&scnt[b], 1u);
                if (slot < DEPTH) stag[b * DEPTH + slot] = rec;
                else {   // rare escape (>=3.5 sigma bucket fill): direct, cursor+1
                    u32 g = atomicAdd(&gcursor[b], 1u);
                    if (g < CAP) recs[(size_t)b * CAP + g] = rec;
                    else {
                        u32 oi = atomicAdd(ovfcnt, 1u);
                        if (oi < OVFCAP) { ovf[2u*oi] = ss; ovf[2u*oi+1u] = dd; }
                    }
                }
            }
        } else if (e0 < E) {
            for (int e = e0; e < E && e < e0 + 4; ++e) {
                u32 ss = (u32)src[e], dd = (u32)dst[e];
                u32 b   = dd >> BKT_BITS;
                u32 rec = (ss << BKT_BITS) | (dd & (BKT_SIZE - 1));
                u32 slot = atomicAdd(&scnt[b], 1u);
                if (slot < DEPTH) stag[b * DEPTH + slot] = rec;
                else {
                    u32 g = atomicAdd(&gcursor[b], 1u);
                    if (g < CAP) recs[(size_t)b * CAP + g] = rec;
                    else {
                        u32 oi = atomicAdd(ovfcnt, 1u);
                        if (oi < OVFCAP) { ovf[2u*oi] = ss; ovf[2u*oi+1u] = dd; }
                    }
                }
            }
        }
    }
    __syncthreads();
    // wave-transposed flush: bucket b is wave-uniform; lanes write a contiguous run.
    int w = tid >> 6, l = tid & 63;
    for (int b = w; b < NB; b += (BIN_T / 64)) {
        u32 c = scnt[b]; if (c > DEPTH) c = DEPTH;
        if (c == 0u) continue;                    // wave-uniform branch
        u32 g = 0u;
        if (l == 0) g = atomicAdd(&gcursor[b], c);
        g = __shfl(g, 0);
        if (g + c <= CAP) {
            if ((u32)l < c)
                recs[(size_t)b * CAP + g + l] = stag[b * DEPTH + l];
        } else {   // statistical never (5.7 sigma total): route to ovf pairs
            if ((u32)l < c) {
                u32 rec = stag[b * DEPTH + l];
                u32 oi = atomicAdd(ovfcnt, 1u);
                if (oi < OVFCAP) {
                    ovf[2u*oi]    = rec >> BKT_BITS;
                    ovf[2u*oi+1u] = ((u32)b << BKT_BITS) | (rec & (BKT_SIZE - 1));
                }
            }
        }
    }
}

// SPLIT blocks per bucket: LDS histogram of a slice -> global atomic merge into deg.
__global__ void __launch_bounds__(HA_T, 8)
hist_kernel(const u32* __restrict__ recs, const u32* __restrict__ gcursor,
            const u32* __restrict__ ovfcnt, const u32* __restrict__ ovf,
            u32* __restrict__ deg, u32 CAP) {
    __shared__ u32 hh[BKT_SIZE];   // 16 KB
    int tid = threadIdx.x;
    int b = blockIdx.x >> 2;
    int split = blockIdx.x & 3;
    for (int j = tid; j < BKT_SIZE; j += HA_T) hh[j] = 0u;
    if (blockIdx.x == 0) {   // overflow edges via global atomics (expected ~0)
        u32 on = *ovfcnt; if (on > OVFCAP) on = OVFCAP;
        for (u32 k = tid; k < on; k += HA_T) atomicAdd(&deg[ovf[2u*k+1u]], 1u);
    }
    __syncthreads();
    u32 cnt = gcursor[b]; if (cnt > CAP) cnt = CAP;
    u32 chunk = (((cnt + SPLIT - 1) / SPLIT) + 3u) & ~3u;   // 16B-aligned slices
    u32 start = split * chunk; if (start > cnt) start = cnt;
    u32 end = start + chunk;   if (end > cnt)   end = cnt;
    const u32* rp = recs + (size_t)b * CAP;
    u32 nv = (end - start) >> 2;
    const iv4* rp4 = reinterpret_cast<const iv4*>(rp + start);
    for (u32 v = tid; v < nv; v += HA_T) {
        iv4 r = __builtin_nontemporal_load(rp4 + v);
        atomicAdd(&hh[((u32)r.x) & (BKT_SIZE - 1)], 1u);
        atomicAdd(&hh[((u32)r.y) & (BKT_SIZE - 1)], 1u);
        atomicAdd(&hh[((u32)r.z) & (BKT_SIZE - 1)], 1u);
        atomicAdd(&hh[((u32)r.w) & (BKT_SIZE - 1)], 1u);
    }
    for (u32 k = start + (nv << 2) + tid; k < end; k += HA_T)
        atomicAdd(&hh[rp[k] & (BKT_SIZE - 1)], 1u);
    __syncthreads();
    int nid0 = b << BKT_BITS;
    for (int j = tid; j < BKT_SIZE; j += HA_T) {
        u32 v = hh[j];
        if (v) atomicAdd(&deg[nid0 + j], v);
    }
}

// deg -> dinv, s; seed acc (aliases deg) with s to account for the self-loop.
__global__ void node_kernel2(const float* __restrict__ x, u32* __restrict__ degacc,
                             const float* __restrict__ W,
                             float* __restrict__ dinv, float* __restrict__ s, int N) {
    int i = (blockIdx.x * blockDim.x + threadIdx.x) << 2;
    float W0 = W[0];
    if (i + 3 < N) {
        iv4 d  = *reinterpret_cast<const iv4*>(degacc + i);
        fv4 xv = *reinterpret_cast<const fv4*>(x + i);
        fv4 dv, sv;
#pragma unroll
        for (int j = 0; j < 4; ++j) {
            float di = rsqrtf((float)((u32)d[j] + 1u));
            dv[j] = di;
            sv[j] = xv[j] * W0 * di;
        }
        *reinterpret_cast<fv4*>(dinv + i) = dv;
        *reinterpret_cast<fv4*>(s + i)    = sv;
        *reinterpret_cast<fv4*>(reinterpret_cast<float*>(degacc) + i) = sv;
    } else {
        for (; i < N; ++i) {
            u32 d = degacc[i];
            float di = rsqrtf((float)(d + 1u));
            float si = x[i] * W0 * di;
            dinv[i] = di; s[i] = si;
            reinterpret_cast<float*>(degacc)[i] = si;
        }
    }
}

// SPLIT blocks per bucket: gather s[src], LDS f32 accumulate, merge into acc.
__global__ void __launch_bounds__(HA_T, 8)
agg_kernel(const u32* __restrict__ recs, const u32* __restrict__ gcursor,
           const u32* __restrict__ ovfcnt, const u32* __restrict__ ovf,
           const float* __restrict__ s, float* __restrict__ acc, u32 CAP) {
    __shared__ float aa[BKT_SIZE];   // 16 KB
    int tid = threadIdx.x;
    int b = blockIdx.x >> 2;
    int split = blockIdx.x & 3;
    for (int j = tid; j < BKT_SIZE; j += HA_T) aa[j] = 0.0f;
    if (blockIdx.x == 0) {
        u32 on = *ovfcnt; if (on > OVFCAP) on = OVFCAP;
        for (u32 k = tid; k < on; k += HA_T)
            atomicAdd(&acc[ovf[2u*k+1u]], s[ovf[2u*k]]);
    }
    __syncthreads();
    u32 cnt = gcursor[b]; if (cnt > CAP) cnt = CAP;
    u32 chunk = (((cnt + SPLIT - 1) / SPLIT) + 3u) & ~3u;
    u32 start = split * chunk; if (start > cnt) start = cnt;
    u32 end = start + chunk;   if (end > cnt)   end = cnt;
    const u32* rp = recs + (size_t)b * CAP;
    u32 nv = (end - start) >> 2;
    const iv4* rp4 = reinterpret_cast<const iv4*>(rp + start);
    for (u32 v = tid; v < nv; v += HA_T) {
        iv4 r = __builtin_nontemporal_load(rp4 + v);
        atomicAdd(&aa[((u32)r.x) & (BKT_SIZE - 1)], s[((u32)r.x) >> BKT_BITS]);
        atomicAdd(&aa[((u32)r.y) & (BKT_SIZE - 1)], s[((u32)r.y) >> BKT_BITS]);
        atomicAdd(&aa[((u32)r.z) & (BKT_SIZE - 1)], s[((u32)r.z) >> BKT_BITS]);
        atomicAdd(&aa[((u32)r.w) & (BKT_SIZE - 1)], s[((u32)r.w) >> BKT_BITS]);
    }
    for (u32 k = start + (nv << 2) + tid; k < end; k += HA_T) {
        u32 r = rp[k];
        atomicAdd(&aa[r & (BKT_SIZE - 1)], s[r >> BKT_BITS]);
    }
    __syncthreads();
    int nid0 = b << BKT_BITS;
    for (int j = tid; j < BKT_SIZE; j += HA_T) {
        float v = aa[j];
        if (v != 0.0f) atomicAdd(&acc[nid0 + j], v);
    }
}

__global__ void out_kernel2(const u32* __restrict__ degacc, const float* __restrict__ dinv,
                            const float* __restrict__ bb, float* __restrict__ out, int N) {
    int i = (blockIdx.x * blockDim.x + threadIdx.x) << 2;
    float b0 = bb[0];
    const float* accf = reinterpret_cast<const float*>(degacc);
    if (i + 3 < N) {
        fv4 a  = *reinterpret_cast<const fv4*>(accf + i);
        fv4 dv = *reinterpret_cast<const fv4*>(dinv + i);
        fv4 o;
#pragma unroll
        for (int j = 0; j < 4; ++j) {
            float z = dv[j] * a[j] + b0;
            o[j] = 1.0f / (1.0f + expf(-z));
        }
        *reinterpret_cast<fv4*>(out + i) = o;
    } else {
        for (; i < N; ++i) {
            float z = dinv[i] * accf[i] + b0;
            out[i] = 1.0f / (1.0f + expf(-z));
        }
    }
}

// ---------------- fallback path ----------------
__global__ void zero_kernel(int* __restrict__ p, int n) {
    int i = blockIdx.x * blockDim.x + threadIdx.x;
    if (i < n) p[i] = 0;
}
__global__ void deg_kernel(const int* __restrict__ dst, int* __restrict__ deg, int E) {
    int i = (blockIdx.x * blockDim.x + threadIdx.x) * 4;
    if (i + 3 < E) {
        int4 d = *reinterpret_cast<const int4*>(dst + i);
        atomicAdd(&deg[d.x], 1); atomicAdd(&deg[d.y], 1);
        atomicAdd(&deg[d.z], 1); atomicAdd(&deg[d.w], 1);
    } else {
        for (int k = i; k < E; ++k) atomicAdd(&deg[dst[k]], 1);
    }
}
__global__ void node_kernel(const float* __restrict__ x, const int* __restrict__ deg,
                            const float* __restrict__ W, float* __restrict__ s,
                            float* __restrict__ dinv, float* __restrict__ acc, int N) {
    int i = blockIdx.x * blockDim.x + threadIdx.x;
    if (i < N) {
        float di = rsqrtf((float)(deg[i] + 1));
        float si = x[i] * W[0] * di;
        dinv[i] = di; s[i] = si; acc[i] = si;
    }
}
__global__ void scatter_kernel(const int* __restrict__ src, const int* __restrict__ dst,
                               const float* __restrict__ s, float* __restrict__ acc, int E) {
    int i = (blockIdx.x * blockDim.x + threadIdx.x) * 4;
    if (i + 3 < E) {
        int4 sv = *reinterpret_cast<const int4*>(src + i);
        int4 dv = *reinterpret_cast<const int4*>(dst + i);
        atomicAdd(&acc[dv.x], s[sv.x]); atomicAdd(&acc[dv.y], s[sv.y]);
        atomicAdd(&acc[dv.z], s[sv.z]); atomicAdd(&acc[dv.w], s[sv.w]);
    } else {
        for (int k = i; k < E; ++k) atomicAdd(&acc[dst[k]], s[src[k]]);
    }
}
__global__ void out_kernel(const float* __restrict__ acc, const float* __restrict__ dinv,
                           const float* __restrict__ b, float* __restrict__ out, int N) {
    int i = blockIdx.x * blockDim.x + threadIdx.x;
    if (i < N) {
        float z = dinv[i] * acc[i] + b[0];
        out[i] = 1.0f / (1.0f + expf(-z));
    }
}

extern "C" void kernel_launch(void* const* d_in, const int* in_sizes, int n_in,
                              void* d_out, int out_size, void* d_ws, size_t ws_size,
                              hipStream_t stream) {
    const int N = in_sizes[0];
    const int E = in_sizes[1] / 2;
    const float* x  = (const float*)d_in[0];
    const int*   ei = (const int*)d_in[1];
    const float* W  = (const float*)d_in[2];
    const float* b  = (const float*)d_in[3];
    float* out = (float*)d_out;

    const int* srcp = ei;
    const int* dstp = ei + E;
    const int T = 256;

    const int NB = (N + BKT_SIZE - 1) >> BKT_BITS;          // 245 for N=1M
    // fixed per-bucket capacity = expected count + 5.7 sigma, 64-aligned
    u64 meanCnt = (N > 0) ? (((u64)E << BKT_BITS) / (u64)N) : 0ull;
    const u32 CAP = (u32)((meanCnt + 2048ull + 63ull) & ~63ull);
    const size_t recCap   = (size_t)NB * CAP;
    const size_t off_cur  = recCap;                       // gcursor: NBMAX
    const size_t off_ovfc = off_cur + NBMAX;              // ovfcnt: 1 (+pad 15)
    const size_t off_ovf  = off_ovfc + 16;                // ovf: 2*OVFCAP
    const size_t off_deg  = off_ovf + 2 * (size_t)OVFCAP; // deg/acc: N
    const size_t off_dinv = off_deg + (size_t)N;          // dinv: N
    const size_t off_s    = off_dinv + (size_t)N;         // s: N
    const size_t need = (off_s + (size_t)N) * 4;

    if (N <= (1 << 20) && NB <= NBMAX && (N & 15) == 0 && (E & 3) == 0 &&
        E > 0 && ws_size >= need) {
        u32* p = (u32*)d_ws;
        u32*   recs    = p;
        u32*   gcursor = p + off_cur;
        u32*   ovfcnt  = p + off_ovfc;
        u32*   ovf     = p + off_ovf;
        u32*   deg     = p + off_deg;    // becomes acc (float) after node_kernel2
        float* dinv    = (float*)(p + off_dinv);
        float* s       = (float*)(p + off_s);

        zero_u32<<<(NBMAX + 16 + T - 1) / T, T, 0, stream>>>(gcursor, NBMAX + 16);
        zero_u32<<<(N + T - 1) / T, T, 0, stream>>>(deg, N);
        bin_kernel4<<<(E + TILE - 1) / TILE, BIN_T, 0, stream>>>(
            srcp, dstp, recs, gcursor, ovfcnt, ovf, E, NB, CAP);
        hist_kernel<<<NB * SPLIT, HA_T, 0, stream>>>(recs, gcursor, ovfcnt, ovf, deg, CAP);
        node_kernel2<<<((N + 3) / 4 + T - 1) / T, T, 0, stream>>>(x, deg, W, dinv, s, N);
        agg_kernel<<<NB * SPLIT, HA_T, 0, stream>>>(
            recs, gcursor, ovfcnt, ovf, s, (float*)deg, CAP);
        out_kernel2<<<((N + 3) / 4 + T - 1) / T, T, 0, stream>>>(deg, dinv, b, out, N);
    } else {
        char* ws = (char*)d_ws;
        int*   deg  = (int*)ws;
        float* s    = (float*)(ws + (size_t)N * 4);
        float* dinv = (float*)(ws + (size_t)N * 8);
        float* acc  = (float*)deg;
        const int blocksN = (N + T - 1) / T;
        const int blocksE = ((E + 3) / 4 + T - 1) / T;
        zero_kernel<<<blocksN, T, 0, stream>>>(deg, N);
        deg_kernel<<<blocksE, T, 0, stream>>>(dstp, deg, E);
        node_kernel<<<blocksN, T, 0, stream>>>(x, deg, W, s, dinv, acc, N);
        scatter_kernel<<<blocksE, T, 0, stream>>>(srcp, dstp, s, acc, E);
        out_kernel<<<blocksN, T, 0, stream>>>(acc, dinv, b, out, N);
    }
}

// Round 5
// 670.287 us; speedup vs baseline: 6.1125x; 6.1125x over previous
//
#include <hip/hip_runtime.h>
#include <math.h>

typedef unsigned int u32;
typedef unsigned long long u64;
typedef int iv4 __attribute__((ext_vector_type(4)));
typedef float fv4 __attribute__((ext_vector_type(4)));

#define BKT_BITS 12
#define BKT_SIZE 4096
#define NBMAX    256
#define DEPTH    31          // odd stride kills slot%32 same-bank ingest pattern;
                             // 31.0KB stag + 1KB scnt = 32KB -> 5 blocks/CU (r0 had 4)
#define BIN_T    256
#define TILE     4096        // r0-proven: 4 rounds x 256 thr x int4, mean fill 16.7
#define SPLIT    4           // sub-blocks per bucket in hist/agg
#define HA_T     512
#define OVFCAP   131072u     // overflow edge capacity (u32 pairs, 1 MB)

// ---------------- fast path ----------------

__global__ void zero_u32(u32* __restrict__ p, int n) {
    int i = blockIdx.x * blockDim.x + threadIdx.x;
    if (i < n) p[i] = 0u;
}

// r0-proven skeleton: oversubscribed grid (7813 blocks), LDS staging, ONE
// parallel thread-per-bucket flush at block end (r4 lesson: never serialize
// contended cursor atomics into a dependent per-wave chain).
// Only change vs r0/r2: DEPTH=31 (odd stride) + TILE=4096.
__global__ void __launch_bounds__(BIN_T)
bin_kernel5(const int* __restrict__ src, const int* __restrict__ dst,
            u32* __restrict__ recs, u32* __restrict__ gcursor,
            u32* __restrict__ ovfcnt, u32* __restrict__ ovf,
            int E, int NB, u32 CAP) {
    __shared__ u32 stag[NBMAX * DEPTH];   // 31 KB
    __shared__ u32 scnt[NBMAX];           // 1 KB -> 32 KB total
    int tid = threadIdx.x;
    for (int t = tid; t < NBMAX; t += BIN_T) scnt[t] = 0u;
    __syncthreads();
    int base = blockIdx.x * TILE;
#pragma unroll
    for (int r = 0; r < TILE / (BIN_T * 4); ++r) {
        int v  = (base >> 2) + r * BIN_T + tid;   // int4 index
        int e0 = v << 2;
        if (e0 + 3 < E) {
            iv4 s4 = __builtin_nontemporal_load(reinterpret_cast<const iv4*>(src) + v);
            iv4 d4 = __builtin_nontemporal_load(reinterpret_cast<const iv4*>(dst) + v);
#pragma unroll
            for (int k = 0; k < 4; ++k) {
                u32 ss = (u32)s4[k], dd = (u32)d4[k];
                u32 b   = dd >> BKT_BITS;
                u32 rec = (ss << BKT_BITS) | (dd & (BKT_SIZE - 1));
                u32 slot = atomicAdd(&scnt[b], 1u);
                if (slot < DEPTH) stag[b * DEPTH + slot] = rec;
                else {   // rare escape (~3.5 sigma bucket fill): direct store
                    u32 g = atomicAdd(&gcursor[b], 1u);
                    if (g < CAP) recs[(size_t)b * CAP + g] = rec;
                    else {
                        u32 oi = atomicAdd(ovfcnt, 1u);
                        if (oi < OVFCAP) { ovf[2u*oi] = ss; ovf[2u*oi+1u] = dd; }
                    }
                }
            }
        } else if (e0 < E) {
            for (int e = e0; e < E && e < e0 + 4; ++e) {
                u32 ss = (u32)src[e], dd = (u32)dst[e];
                u32 b   = dd >> BKT_BITS;
                u32 rec = (ss << BKT_BITS) | (dd & (BKT_SIZE - 1));
                u32 slot = atomicAdd(&scnt[b], 1u);
                if (slot < DEPTH) stag[b * DEPTH + slot] = rec;
                else {
                    u32 g = atomicAdd(&gcursor[b], 1u);
                    if (g < CAP) recs[(size_t)b * CAP + g] = rec;
                    else {
                        u32 oi = atomicAdd(ovfcnt, 1u);
                        if (oi < OVFCAP) { ovf[2u*oi] = ss; ovf[2u*oi+1u] = dd; }
                    }
                }
            }
        }
    }
    __syncthreads();
    // thread t flushes bucket t: parallel wave-wide cursor atomics (r0-proven),
    // serial (independent) stores of c<=31 contiguous u32s.
    int t = tid;
    if (t < NB) {
        u32 c = scnt[t]; if (c > DEPTH) c = DEPTH;
        if (c > 0u) {
            u32 g = atomicAdd(&gcursor[t], c);
            size_t bp = (size_t)t * CAP;
            if (g + c <= CAP) {
                for (u32 k = 0; k < c; ++k) recs[bp + g + k] = stag[t * DEPTH + k];
            } else {   // statistical never (5.7 sigma): route to ovf pairs
                for (u32 k = 0; k < c; ++k) {
                    u32 rec = stag[t * DEPTH + k];
                    u32 pos = g + k;
                    if (pos < CAP) recs[bp + pos] = rec;
                    else {
                        u32 oi = atomicAdd(ovfcnt, 1u);
                        if (oi < OVFCAP) {
                            ovf[2u*oi]    = rec >> BKT_BITS;
                            ovf[2u*oi+1u] = ((u32)t << BKT_BITS) | (rec & (BKT_SIZE - 1));
                        }
                    }
                }
            }
        }
    }
}

// SPLIT blocks per bucket: LDS histogram of a slice -> global atomic merge into deg.
__global__ void __launch_bounds__(HA_T, 8)
hist_kernel(const u32* __restrict__ recs, const u32* __restrict__ gcursor,
            const u32* __restrict__ ovfcnt, const u32* __restrict__ ovf,
            u32* __restrict__ deg, u32 CAP) {
    __shared__ u32 hh[BKT_SIZE];   // 16 KB
    int tid = threadIdx.x;
    int b = blockIdx.x >> 2;
    int split = blockIdx.x & 3;
    for (int j = tid; j < BKT_SIZE; j += HA_T) hh[j] = 0u;
    if (blockIdx.x == 0) {   // overflow edges via global atomics (expected ~0)
        u32 on = *ovfcnt; if (on > OVFCAP) on = OVFCAP;
        for (u32 k = tid; k < on; k += HA_T) atomicAdd(&deg[ovf[2u*k+1u]], 1u);
    }
    __syncthreads();
    u32 cnt = gcursor[b]; if (cnt > CAP) cnt = CAP;
    u32 chunk = (((cnt + SPLIT - 1) / SPLIT) + 3u) & ~3u;   // 16B-aligned slices
    u32 start = split * chunk; if (start > cnt) start = cnt;
    u32 end = start + chunk;   if (end > cnt)   end = cnt;
    const u32* rp = recs + (size_t)b * CAP;
    u32 nv = (end - start) >> 2;
    const iv4* rp4 = reinterpret_cast<const iv4*>(rp + start);
    for (u32 v = tid; v < nv; v += HA_T) {
        iv4 r = __builtin_nontemporal_load(rp4 + v);
        atomicAdd(&hh[((u32)r.x) & (BKT_SIZE - 1)], 1u);
        atomicAdd(&hh[((u32)r.y) & (BKT_SIZE - 1)], 1u);
        atomicAdd(&hh[((u32)r.z) & (BKT_SIZE - 1)], 1u);
        atomicAdd(&hh[((u32)r.w) & (BKT_SIZE - 1)], 1u);
    }
    for (u32 k = start + (nv << 2) + tid; k < end; k += HA_T)
        atomicAdd(&hh[rp[k] & (BKT_SIZE - 1)], 1u);
    __syncthreads();
    int nid0 = b << BKT_BITS;
    for (int j = tid; j < BKT_SIZE; j += HA_T) {
        u32 v = hh[j];
        if (v) atomicAdd(&deg[nid0 + j], v);
    }
}

// deg -> dinv, s; seed acc (aliases deg) with s to account for the self-loop.
__global__ void node_kernel2(const float* __restrict__ x, u32* __restrict__ degacc,
                             const float* __restrict__ W,
                             float* __restrict__ dinv, float* __restrict__ s, int N) {
    int i = (blockIdx.x * blockDim.x + threadIdx.x) << 2;
    float W0 = W[0];
    if (i + 3 < N) {
        iv4 d  = *reinterpret_cast<const iv4*>(degacc + i);
        fv4 xv = *reinterpret_cast<const fv4*>(x + i);
        fv4 dv, sv;
#pragma unroll
        for (int j = 0; j < 4; ++j) {
            float di = rsqrtf((float)((u32)d[j] + 1u));
            dv[j] = di;
            sv[j] = xv[j] * W0 * di;
        }
        *reinterpret_cast<fv4*>(dinv + i) = dv;
        *reinterpret_cast<fv4*>(s + i)    = sv;
        *reinterpret_cast<fv4*>(reinterpret_cast<float*>(degacc) + i) = sv;
    } else {
        for (; i < N; ++i) {
            u32 d = degacc[i];
            float di = rsqrtf((float)(d + 1u));
            float si = x[i] * W0 * di;
            dinv[i] = di; s[i] = si;
            reinterpret_cast<float*>(degacc)[i] = si;
        }
    }
}

// SPLIT blocks per bucket: gather s[src], LDS f32 accumulate, merge into acc.
__global__ void __launch_bounds__(HA_T, 8)
agg_kernel(const u32* __restrict__ recs, const u32* __restrict__ gcursor,
           const u32* __restrict__ ovfcnt, const u32* __restrict__ ovf,
           const float* __restrict__ s, float* __restrict__ acc, u32 CAP) {
    __shared__ float aa[BKT_SIZE];   // 16 KB
    int tid = threadIdx.x;
    int b = blockIdx.x >> 2;
    int split = blockIdx.x & 3;
    for (int j = tid; j < BKT_SIZE; j += HA_T) aa[j] = 0.0f;
    if (blockIdx.x == 0) {
        u32 on = *ovfcnt; if (on > OVFCAP) on = OVFCAP;
        for (u32 k = tid; k < on; k += HA_T)
            atomicAdd(&acc[ovf[2u*k+1u]], s[ovf[2u*k]]);
    }
    __syncthreads();
    u32 cnt = gcursor[b]; if (cnt > CAP) cnt = CAP;
    u32 chunk = (((cnt + SPLIT - 1) / SPLIT) + 3u) & ~3u;
    u32 start = split * chunk; if (start > cnt) start = cnt;
    u32 end = start + chunk;   if (end > cnt)   end = cnt;
    const u32* rp = recs + (size_t)b * CAP;
    u32 nv = (end - start) >> 2;
    const iv4* rp4 = reinterpret_cast<const iv4*>(rp + start);
    for (u32 v = tid; v < nv; v += HA_T) {
        iv4 r = __builtin_nontemporal_load(rp4 + v);
        atomicAdd(&aa[((u32)r.x) & (BKT_SIZE - 1)], s[((u32)r.x) >> BKT_BITS]);
        atomicAdd(&aa[((u32)r.y) & (BKT_SIZE - 1)], s[((u32)r.y) >> BKT_BITS]);
        atomicAdd(&aa[((u32)r.z) & (BKT_SIZE - 1)], s[((u32)r.z) >> BKT_BITS]);
        atomicAdd(&aa[((u32)r.w) & (BKT_SIZE - 1)], s[((u32)r.w) >> BKT_BITS]);
    }
    for (u32 k = start + (nv << 2) + tid; k < end; k += HA_T) {
        u32 r = rp[k];
        atomicAdd(&aa[r & (BKT_SIZE - 1)], s[r >> BKT_BITS]);
    }
    __syncthreads();
    int nid0 = b << BKT_BITS;
    for (int j = tid; j < BKT_SIZE; j += HA_T) {
        float v = aa[j];
        if (v != 0.0f) atomicAdd(&acc[nid0 + j], v);
    }
}

__global__ void out_kernel2(const u32* __restrict__ degacc, const float* __restrict__ dinv,
                            const float* __restrict__ bb, float* __restrict__ out, int N) {
    int i = (blockIdx.x * blockDim.x + threadIdx.x) << 2;
    float b0 = bb[0];
    const float* accf = reinterpret_cast<const float*>(degacc);
    if (i + 3 < N) {
        fv4 a  = *reinterpret_cast<const fv4*>(accf + i);
        fv4 dv = *reinterpret_cast<const fv4*>(dinv + i);
        fv4 o;
#pragma unroll
        for (int j = 0; j < 4; ++j) {
            float z = dv[j] * a[j] + b0;
            o[j] = 1.0f / (1.0f + expf(-z));
        }
        *reinterpret_cast<fv4*>(out + i) = o;
    } else {
        for (; i < N; ++i) {
            float z = dinv[i] * accf[i] + b0;
            out[i] = 1.0f / (1.0f + expf(-z));
        }
    }
}

// ---------------- fallback path ----------------
__global__ void zero_kernel(int* __restrict__ p, int n) {
    int i = blockIdx.x * blockDim.x + threadIdx.x;
    if (i < n) p[i] = 0;
}
__global__ void deg_kernel(const int* __restrict__ dst, int* __restrict__ deg, int E) {
    int i = (blockIdx.x * blockDim.x + threadIdx.x) * 4;
    if (i + 3 < E) {
        int4 d = *reinterpret_cast<const int4*>(dst + i);
        atomicAdd(&deg[d.x], 1); atomicAdd(&deg[d.y], 1);
        atomicAdd(&deg[d.z], 1); atomicAdd(&deg[d.w], 1);
    } else {
        for (int k = i; k < E; ++k) atomicAdd(&deg[dst[k]], 1);
    }
}
__global__ void node_kernel(const float* __restrict__ x, const int* __restrict__ deg,
                            const float* __restrict__ W, float* __restrict__ s,
                            float* __restrict__ dinv, float* __restrict__ acc, int N) {
    int i = blockIdx.x * blockDim.x + threadIdx.x;
    if (i < N) {
        float di = rsqrtf((float)(deg[i] + 1));
        float si = x[i] * W[0] * di;
        dinv[i] = di; s[i] = si; acc[i] = si;
    }
}
__global__ void scatter_kernel(const int* __restrict__ src, const int* __restrict__ dst,
                               const float* __restrict__ s, float* __restrict__ acc, int E) {
    int i = (blockIdx.x * blockDim.x + threadIdx.x) * 4;
    if (i + 3 < E) {
        int4 sv = *reinterpret_cast<const int4*>(src + i);
        int4 dv = *reinterpret_cast<const int4*>(dst + i);
        atomicAdd(&acc[dv.x], s[sv.x]); atomicAdd(&acc[dv.y], s[sv.y]);
        atomicAdd(&acc[dv.z], s[sv.z]); atomicAdd(&acc[dv.w], s[sv.w]);
    } else {
        for (int k = i; k < E; ++k) atomicAdd(&acc[dst[k]], s[src[k]]);
    }
}
__global__ void out_kernel(const float* __restrict__ acc, const float* __restrict__ dinv,
                           const float* __restrict__ b, float* __restrict__ out, int N) {
    int i = blockIdx.x * blockDim.x + threadIdx.x;
    if (i < N) {
        float z = dinv[i] * acc[i] + b[0];
        out[i] = 1.0f / (1.0f + expf(-z));
    }
}

extern "C" void kernel_launch(void* const* d_in, const int* in_sizes, int n_in,
                              void* d_out, int out_size, void* d_ws, size_t ws_size,
                              hipStream_t stream) {
    const int N = in_sizes[0];
    const int E = in_sizes[1] / 2;
    const float* x  = (const float*)d_in[0];
    const int*   ei = (const int*)d_in[1];
    const float* W  = (const float*)d_in[2];
    const float* b  = (const float*)d_in[3];
    float* out = (float*)d_out;

    const int* srcp = ei;
    const int* dstp = ei + E;
    const int T = 256;

    const int NB = (N + BKT_SIZE - 1) >> BKT_BITS;          // 245 for N=1M
    // fixed per-bucket capacity = expected count + 5.7 sigma, 64-aligned
    u64 meanCnt = (N > 0) ? (((u64)E << BKT_BITS) / (u64)N) : 0ull;
    const u32 CAP = (u32)((meanCnt + 2048ull + 63ull) & ~63ull);
    const size_t recCap   = (size_t)NB * CAP;
    const size_t off_cur  = recCap;                       // gcursor: NBMAX
    const size_t off_ovfc = off_cur + NBMAX;              // ovfcnt: 1 (+pad 15)
    const size_t off_ovf  = off_ovfc + 16;                // ovf: 2*OVFCAP
    const size_t off_deg  = off_ovf + 2 * (size_t)OVFCAP; // deg/acc: N
    const size_t off_dinv = off_deg + (size_t)N;          // dinv: N
    const size_t off_s    = off_dinv + (size_t)N;         // s: N
    const size_t need = (off_s + (size_t)N) * 4;

    if (N <= (1 << 20) && NB <= NBMAX && (N & 15) == 0 && (E & 3) == 0 &&
        E > 0 && ws_size >= need) {
        u32* p = (u32*)d_ws;
        u32*   recs    = p;
        u32*   gcursor = p + off_cur;
        u32*   ovfcnt  = p + off_ovfc;
        u32*   ovf     = p + off_ovf;
        u32*   deg     = p + off_deg;    // becomes acc (float) after node_kernel2
        float* dinv    = (float*)(p + off_dinv);
        float* s       = (float*)(p + off_s);

        zero_u32<<<(NBMAX + 16 + T - 1) / T, T, 0, stream>>>(gcursor, NBMAX + 16);
        zero_u32<<<(N + T - 1) / T, T, 0, stream>>>(deg, N);
        bin_kernel5<<<(E + TILE - 1) / TILE, BIN_T, 0, stream>>>(
            srcp, dstp, recs, gcursor, ovfcnt, ovf, E, NB, CAP);
        hist_kernel<<<NB * SPLIT, HA_T, 0, stream>>>(recs, gcursor, ovfcnt, ovf, deg, CAP);
        node_kernel2<<<((N + 3) / 4 + T - 1) / T, T, 0, stream>>>(x, deg, W, dinv, s, N);
        agg_kernel<<<NB * SPLIT, HA_T, 0, stream>>>(
            recs, gcursor, ovfcnt, ovf, s, (float*)deg, CAP);
        out_kernel2<<<((N + 3) / 4 + T - 1) / T, T, 0, stream>>>(deg, dinv, b, out, N);
    } else {
        char* ws = (char*)d_ws;
        int*   deg  = (int*)ws;
        float* s    = (float*)(ws + (size_t)N * 4);
        float* dinv = (float*)(ws + (size_t)N * 8);
        float* acc  = (float*)deg;
        const int blocksN = (N + T - 1) / T;
        const int blocksE = ((E + 3) / 4 + T - 1) / T;
        zero_kernel<<<blocksN, T, 0, stream>>>(deg, N);
        deg_kernel<<<blocksE, T, 0, stream>>>(dstp, deg, E);
        node_kernel<<<blocksN, T, 0, stream>>>(x, deg, W, s, dinv, acc, N);
        scatter_kernel<<<blocksE, T, 0, stream>>>(srcp, dstp, s, acc, E);
        out_kernel<<<blocksN, T, 0, stream>>>(acc, dinv, b, out, N);
    }
}